// Round 15
// baseline (55.719 us; speedup 1.0000x reference)
//
#include <hip/hip_runtime.h>

#define BATCH 8
#define CIN 64
#define H 128
#define W 128
#define OCH 64
#define HW (H*W)
#define OFFCH 18

using f16x8 = __attribute__((ext_vector_type(8))) _Float16;
using f32x4 = __attribute__((ext_vector_type(4))) float;

template<bool V> struct BoolC { static constexpr bool value = V; };

static __device__ __forceinline__ int iclamp(int v, int lo, int hi) {
    return v < lo ? lo : (v > hi ? hi : v);
}
static __device__ __forceinline__ f16x8 splat8(_Float16 v) {
    return (f16x8){v, v, v, v, v, v, v, v};
}
static __device__ __forceinline__ unsigned packh2(float a, float b) {
    union { _Float16 h[2]; unsigned u; } pk;
    pk.h[0] = (_Float16)a; pk.h[1] = (_Float16)b;
    return pk.u;
}

// ---------------- prep both weight tensors -> f16 MFMA A-frag order (one launch) ----------------
__global__ __launch_bounds__(256) void prep_w_kernel(
    const float* __restrict__ wd, const float* __restrict__ wo,
    _Float16* __restrict__ wdf, _Float16* __restrict__ wof)
{
    int i = blockIdx.x * 256 + threadIdx.x;   // 55296 total
    if (i < 36864) {
        int j    = i & 7;
        int lane = (i >> 3) & 63;
        int mt   = (i >> 9) & 3;
        int cs   = (i >> 11) & 1;
        int tap  = i >> 12;
        int oc = mt * 16 + (lane & 15);
        int c  = cs * 32 + (lane >> 4) * 8 + j;
        wdf[i] = (_Float16)wd[(oc * CIN + c) * 9 + tap];
    } else if (i < 36864 + 18432) {
        int k = i - 36864;
        int j    = k & 7;
        int lane = (k >> 3) & 63;
        int mt   = (k >> 9) & 1;
        int cs   = (k >> 10) & 1;
        int tap  = k >> 11;
        int oc = mt * 16 + (lane & 15);
        int c  = cs * 32 + (lane >> 4) * 8 + j;
        wof[k] = (oc < OFFCH) ? (_Float16)wo[(oc * CIN + c) * 9 + tap] : (_Float16)0.f;
    }
}

// ---------------- fused: stage(NCHW f32 -> f16 band) + offset conv + deformable conv ----------------
// Grid 256 = (b, yquad); 1024 threads = 16 waves; wave w: row y+(w>>2), px (w&3)*32+{0,16}+l15.
// N=32/wave. Rows [y-2, y+5] staged in LDS (128 KB) directly from x (transpose in registers).
// Bilinear records in producer-lane registers, consumed via __shfl.
// Fallback hoisted: ONE per-wave branch selects a flag-free fast phase-2 (templated).
__global__ __launch_bounds__(1024, 4) void fused_deform_kernel(
    const float* __restrict__ x, const f16x8* __restrict__ wof,
    const f16x8* __restrict__ wdf, const float* __restrict__ bias,
    float* __restrict__ out)
{
    __shared__ _Float16 band[8 * 128 * CIN];       // 128 KB; chunk-swizzled per pixel

    int bid  = blockIdx.x;           // 256
    int b    = bid & 7;              // one batch per XCD
    int y    = (bid >> 3) * 4;       // block covers rows y..y+3
    int tid  = threadIdx.x;
    int lane = tid & 63;
    int wave = tid >> 6;             // 0..15
    int l15  = lane & 15;
    int lk   = lane >> 4;
    int yo   = y + (wave >> 2);      // this wave's output row
    int pxbase = (wave & 3) * 32;
    int p0   = pxbase + l15;         // nt=0 pixel
    int p1   = p0 + 16;              // nt=1 pixel

    int ylo = y - 2 < 0 ? 0 : y - 2;
    int yhi = y + 5 > H - 1 ? H - 1 : y + 5;
    int nrm1 = yhi - ylo;

    const float* xbf = x + (size_t)b * CIN * HW;

    // ---- stage band rows [ylo..yhi] directly from NCHW f32 ----
    {
        int px_s = tid & 127;
        int cg   = tid >> 7;                 // channel group 0..7
        int jp_s = cg ^ (px_s & 7);
        const float* xcg = xbf + (size_t)(cg * 8) * HW + px_s;
        #pragma unroll
        for (int r = 0; r < 8; ++r) {
            int gy = ylo + r;
            if (gy > yhi) break;
            const float* xp = xcg + (size_t)gy * W;
            f16x8 v;
            #pragma unroll
            for (int j = 0; j < 8; ++j) v[j] = (_Float16)xp[(size_t)j * HW];
            *(f16x8*)&band[(((size_t)r * 128 + px_s) * 8 + jp_s) * 8] = v;
        }
    }
    __syncthreads();

    // ======== phase 1: offset conv (M=32 padded, N=32/wave, K=576), B from band ========
    f32x4 oacc[2][2];   // [mt][nt]
    #pragma unroll
    for (int mt = 0; mt < 2; ++mt)
        #pragma unroll
        for (int nt = 0; nt < 2; ++nt) oacc[mt][nt] = (f32x4){0.f, 0.f, 0.f, 0.f};

    #pragma unroll
    for (int tap = 0; tap < 9; ++tap) {
        int ky = tap / 3, kx = tap - 3 * ky;
        int yy = yo - 1 + ky;
        bool iny = (yy >= 0 && yy < H);
        int ry = yy - ylo;
        int pos0 = p0 - 1 + kx;
        int pos1 = p1 - 1 + kx;
        #pragma unroll
        for (int cs = 0; cs < 2; ++cs) {
            const f16x8* wf = wof + (size_t)((tap * 2 + cs) * 2) * 64 + lane;
            f16x8 a0 = wf[0];
            f16x8 a1 = wf[64];
            f16x8 b0 = splat8((_Float16)0.f), b1 = splat8((_Float16)0.f);
            if (iny && pos0 >= 0 && pos0 < W) {
                int jp = (cs * 4 + lk) ^ (pos0 & 7);
                b0 = *(const f16x8*)&band[(((size_t)ry * 128 + pos0) * 8 + jp) * 8];
            }
            if (iny && pos1 >= 0 && pos1 < W) {
                int jp = (cs * 4 + lk) ^ (pos1 & 7);
                b1 = *(const f16x8*)&band[(((size_t)ry * 128 + pos1) * 8 + jp) * 8];
            }
            __builtin_amdgcn_s_setprio(1);
            oacc[0][0] = __builtin_amdgcn_mfma_f32_16x16x32_f16(a0, b0, oacc[0][0], 0, 0, 0);
            oacc[1][0] = __builtin_amdgcn_mfma_f32_16x16x32_f16(a1, b0, oacc[1][0], 0, 0, 0);
            oacc[0][1] = __builtin_amdgcn_mfma_f32_16x16x32_f16(a0, b1, oacc[0][1], 0, 0, 0);
            oacc[1][1] = __builtin_amdgcn_mfma_f32_16x16x32_f16(a1, b1, oacc[1][1], 0, 0, 0);
            __builtin_amdgcn_s_setprio(0);
        }
    }

    // ======== record build into REGISTERS: lane (l15,lk) owns taps {2lk,2lk+1} (+8 if lk==0) ========
    uint4 rcA, rcB, rcC, rcD;                    // [tap even/odd][p0/p1]
    uint4 rc8a = {0,0,0,0}, rc8b = {0,0,0,0};    // tap 8 (valid in lk==0 lanes)
    unsigned ofA, ofB, ofC, ofD, of8a = 0, of8b = 0;

    auto build = [&](int tap, float offy, float offx, int p, uint4& rc, unsigned& of) {
        int ky = tap / 3, kx = tap - 3 * ky;
        float py  = (float)(yo - 1 + ky) + offy;
        float pxf = (float)(p  - 1 + kx) + offx;
        float y0f = floorf(py), x0f = floorf(pxf);
        float fy = py - y0f, fx = pxf - x0f;
        int y0 = (int)y0f, x0 = (int)x0f;
        int y1 = y0 + 1, x1 = x0 + 1;
        float m00 = (1.f - fy) * (1.f - fx);
        float m01 = (1.f - fy) * fx;
        float m10 = fy * (1.f - fx);
        float m11 = fy * fx;
        if (y0 < 0 || y0 >= H) { m00 = 0.f; m01 = 0.f; }
        if (y1 < 0 || y1 >= H) { m10 = 0.f; m11 = 0.f; }
        if (x0 < 0 || x0 >= W) { m00 = 0.f; m10 = 0.f; }
        if (x1 < 0 || x1 >= W) { m01 = 0.f; m11 = 0.f; }
        int y0c = iclamp(y0, 0, H - 1), y1c = iclamp(y1, 0, H - 1);
        int x0c = iclamp(x0, 0, W - 1), x1c = iclamp(x1, 0, W - 1);
        int ry0 = y0c - ylo, ry1 = y1c - ylo;
        unsigned o0 = (ry0 < 0 || ry0 > nrm1) ? 0x8000u : 0u;
        unsigned o1 = (ry1 < 0 || ry1 > nrm1) ? 0x8000u : 0u;
        int r0 = iclamp(ry0, 0, 7), r1 = iclamp(ry1, 0, 7);
        unsigned f0 = (unsigned)(((r0 * 128 + x0c) << 3) | (x0c & 7)) | o0;
        unsigned f1 = (unsigned)(((r0 * 128 + x1c) << 3) | (x1c & 7)) | o0;
        unsigned f2 = (unsigned)(((r1 * 128 + x0c) << 3) | (x0c & 7)) | o1;
        unsigned f3 = (unsigned)(((r1 * 128 + x1c) << 3) | (x1c & 7)) | o1;
        rc.x = packh2(m00, m01);
        rc.y = packh2(m10, m11);
        rc.z = f0 | (f1 << 16);
        rc.w = f2 | (f3 << 16);
        of   = packh2(offy, offx);
    };
    build(2 * lk,     oacc[0][0][0], oacc[0][0][1], p0, rcA, ofA);
    build(2 * lk + 1, oacc[0][0][2], oacc[0][0][3], p0, rcB, ofB);
    build(2 * lk,     oacc[0][1][0], oacc[0][1][1], p1, rcC, ofC);
    build(2 * lk + 1, oacc[0][1][2], oacc[0][1][3], p1, rcD, ofD);
    if (lk == 0) {
        build(8, oacc[1][0][0], oacc[1][0][1], p0, rc8a, of8a);
        build(8, oacc[1][1][0], oacc[1][1][1], p1, rc8b, of8b);
    }

    // hoisted fallback detection: ONE wave-level branch for the whole phase 2
    unsigned flagbits = (rcA.z | rcA.w | rcB.z | rcB.w | rcC.z | rcC.w | rcD.z | rcD.w
                       | rc8a.z | rc8a.w | rc8b.z | rc8b.w) & 0x80008000u;
    bool anyfall = __any(flagbits != 0);

    // ======== phase 2: deformable conv (M=64, N=32/wave, K=576) ========
    f32x4 acc[4][2];   // [mt][nt]
    #pragma unroll
    for (int mt = 0; mt < 4; ++mt)
        #pragma unroll
        for (int nt = 0; nt < 2; ++nt) acc[mt][nt] = (f32x4){0.f, 0.f, 0.f, 0.f};

    const char* bb = (const char*)band;

    auto phase2 = [&](auto fbTag) {
        constexpr bool FB = decltype(fbTag)::value;
        #pragma unroll
        for (int tap = 0; tap < 9; ++tap) {
            int src = (tap < 8) ? ((tap >> 1) * 16 + l15) : l15;

            // A-frags issued FIRST: independent of LDS gathers -> overlap ds_read latency
            f16x8 af[2][4];
            #pragma unroll
            for (int cs = 0; cs < 2; ++cs) {
                const f16x8* wf = wdf + (size_t)((tap * 2 + cs) * 4) * 64 + lane;
                #pragma unroll
                for (int mt = 0; mt < 4; ++mt) af[cs][mt] = wf[mt * 64];
            }

            f16x8 bfr[2][2];   // [cs][nt]
            #pragma unroll
            for (int nt = 0; nt < 2; ++nt) {
                int pp = nt ? p1 : p0;
                uint4 rsel;
                unsigned osel;
                if (tap < 8) {
                    if (tap & 1) { rsel = nt ? rcD : rcB; osel = nt ? ofD : ofB; }
                    else         { rsel = nt ? rcC : rcA; osel = nt ? ofC : ofA; }
                } else         { rsel = nt ? rc8b : rc8a; osel = nt ? of8b : of8a; }
                uint4 rc;
                rc.x = (unsigned)__shfl((int)rsel.x, src, 64);
                rc.y = (unsigned)__shfl((int)rsel.y, src, 64);
                rc.z = (unsigned)__shfl((int)rsel.z, src, 64);
                rc.w = (unsigned)__shfl((int)rsel.w, src, 64);

                union { unsigned u; _Float16 h[2]; } mA, mB;
                mA.u = rc.x; mB.u = rc.y;
                _Float16 h00 = mA.h[0], h01 = mA.h[1], h10 = mB.h[0], h11 = mB.h[1];
                int f0 = rc.z & 0xffff, f1 = rc.z >> 16;
                int f2 = rc.w & 0xffff, f3 = rc.w >> 16;
                int a00 = (((f0 >> 3) & 1023) << 7) + ((lk ^ (f0 & 7)) << 4);
                int a01 = (((f1 >> 3) & 1023) << 7) + ((lk ^ (f1 & 7)) << 4);
                int a10 = (((f2 >> 3) & 1023) << 7) + ((lk ^ (f2 & 7)) << 4);
                int a11 = (((f3 >> 3) & 1023) << 7) + ((lk ^ (f3 & 7)) << 4);

                f16x8 g00 = *(const f16x8*)(bb + a00);
                f16x8 g01 = *(const f16x8*)(bb + a01);
                f16x8 g10 = *(const f16x8*)(bb + a10);
                f16x8 g11 = *(const f16x8*)(bb + a11);
                bfr[0][nt] = g00 * splat8(h00) + g01 * splat8(h01)
                           + g10 * splat8(h10) + g11 * splat8(h11);
                f16x8 k00 = *(const f16x8*)(bb + (a00 ^ 64));
                f16x8 k01 = *(const f16x8*)(bb + (a01 ^ 64));
                f16x8 k10 = *(const f16x8*)(bb + (a10 ^ 64));
                f16x8 k11 = *(const f16x8*)(bb + (a11 ^ 64));
                bfr[1][nt] = k00 * splat8(h00) + k01 * splat8(h01)
                           + k10 * splat8(h10) + k11 * splat8(h11);

                if constexpr (FB) {
                    bool fall = ((rc.z | rc.w) & 0x80008000u) != 0;
                    unsigned ofu = (unsigned)__shfl((int)osel, src, 64);
                    if (fall) {   // rare: corner row outside staged band -> NCHW f32 gather
                        union { unsigned u; _Float16 h[2]; } of;
                        of.u = ofu;
                        float offy = (float)of.h[0], offx = (float)of.h[1];
                        int ky = tap / 3, kx = tap - 3 * ky;
                        float py  = (float)(yo - 1 + ky) + offy;
                        float pxf = (float)(pp - 1 + kx) + offx;
                        float y0f = floorf(py), x0f = floorf(pxf);
                        float fy = py - y0f, fx = pxf - x0f;
                        int y0 = (int)y0f, x0 = (int)x0f;
                        int y1 = y0 + 1, x1 = x0 + 1;
                        float n00 = (1.f - fy) * (1.f - fx);
                        float n01 = (1.f - fy) * fx;
                        float n10 = fy * (1.f - fx);
                        float n11 = fy * fx;
                        if (y0 < 0 || y0 >= H) { n00 = 0.f; n01 = 0.f; }
                        if (y1 < 0 || y1 >= H) { n10 = 0.f; n11 = 0.f; }
                        if (x0 < 0 || x0 >= W) { n00 = 0.f; n10 = 0.f; }
                        if (x1 < 0 || x1 >= W) { n01 = 0.f; n11 = 0.f; }
                        int y0c = iclamp(y0, 0, H - 1), y1c = iclamp(y1, 0, H - 1);
                        int x0c = iclamp(x0, 0, W - 1), x1c = iclamp(x1, 0, W - 1);
                        int i00 = y0c * W + x0c, i01 = y0c * W + x1c;
                        int i10 = y1c * W + x0c, i11 = y1c * W + x1c;
                        #pragma unroll
                        for (int cs = 0; cs < 2; ++cs) {
                            const float* xc = xbf + (size_t)(cs * 32 + lk * 8) * HW;
                            #pragma unroll
                            for (int j = 0; j < 8; ++j) {
                                float v = n00 * xc[i00] + n01 * xc[i01]
                                        + n10 * xc[i10] + n11 * xc[i11];
                                bfr[cs][nt][j] = (_Float16)v;
                                xc += HW;
                            }
                        }
                    }
                }
            }

            __builtin_amdgcn_s_setprio(1);
            #pragma unroll
            for (int cs = 0; cs < 2; ++cs) {
                #pragma unroll
                for (int mt = 0; mt < 4; ++mt) {
                    acc[mt][0] = __builtin_amdgcn_mfma_f32_16x16x32_f16(af[cs][mt], bfr[cs][0], acc[mt][0], 0, 0, 0);
                    acc[mt][1] = __builtin_amdgcn_mfma_f32_16x16x32_f16(af[cs][mt], bfr[cs][1], acc[mt][1], 0, 0, 0);
                }
            }
            __builtin_amdgcn_s_setprio(0);
        }
    };

    if (anyfall) phase2(BoolC<true>{});
    else         phase2(BoolC<false>{});

    #pragma unroll
    for (int mt = 0; mt < 4; ++mt) {
        #pragma unroll
        for (int nt = 0; nt < 2; ++nt) {
            int pp = nt ? p1 : p0;
            #pragma unroll
            for (int r = 0; r < 4; ++r) {
                int oc = mt * 16 + lk * 4 + r;
                out[((size_t)b * OCH + oc) * HW + (size_t)yo * W + pp] = acc[mt][nt][r] + bias[oc];
            }
        }
    }
}

extern "C" void kernel_launch(void* const* d_in, const int* in_sizes, int n_in,
                              void* d_out, int out_size, void* d_ws, size_t ws_size,
                              hipStream_t stream) {
    const float* x     = (const float*)d_in[0];
    const float* w_off = (const float*)d_in[1];
    const float* w_def = (const float*)d_in[2];
    const float* b_def = (const float*)d_in[3];
    float* out = (float*)d_out;

    _Float16* wdf = (_Float16*)d_ws;                 // 36,864 f16
    _Float16* wof = wdf + 36864;                     // 18,432 f16

    prep_w_kernel<<<(36864 + 18432 + 255) / 256, 256, 0, stream>>>(w_def, w_off, wdf, wof);
    fused_deform_kernel<<<BATCH * H / 4, 1024, 0, stream>>>(
        x, (const f16x8*)wof, (const f16x8*)wdf, b_def, out);
}

// Round 16
// 48.084 us; speedup vs baseline: 1.1588x; 1.1588x over previous
//
#include <hip/hip_runtime.h>

#define BATCH 8
#define CIN 64
#define H 128
#define W 128
#define OCH 64
#define HW (H*W)
#define OFFCH 18

using f16x8 = __attribute__((ext_vector_type(8))) _Float16;
using f32x4 = __attribute__((ext_vector_type(4))) float;

static __device__ __forceinline__ int iclamp(int v, int lo, int hi) {
    return v < lo ? lo : (v > hi ? hi : v);
}
static __device__ __forceinline__ f16x8 splat8(_Float16 v) {
    return (f16x8){v, v, v, v, v, v, v, v};
}
static __device__ __forceinline__ unsigned packh2(float a, float b) {
    union { _Float16 h[2]; unsigned u; } pk;
    pk.h[0] = (_Float16)a; pk.h[1] = (_Float16)b;
    return pk.u;
}

// ---------------- prep both weight tensors -> f16 MFMA A-frag order (one launch) ----------------
__global__ __launch_bounds__(256) void prep_w_kernel(
    const float* __restrict__ wd, const float* __restrict__ wo,
    _Float16* __restrict__ wdf, _Float16* __restrict__ wof)
{
    int i = blockIdx.x * 256 + threadIdx.x;   // 55296 total
    if (i < 36864) {
        int j    = i & 7;
        int lane = (i >> 3) & 63;
        int mt   = (i >> 9) & 3;
        int cs   = (i >> 11) & 1;
        int tap  = i >> 12;
        int oc = mt * 16 + (lane & 15);
        int c  = cs * 32 + (lane >> 4) * 8 + j;
        wdf[i] = (_Float16)wd[(oc * CIN + c) * 9 + tap];
    } else if (i < 36864 + 18432) {
        int k = i - 36864;
        int j    = k & 7;
        int lane = (k >> 3) & 63;
        int mt   = (k >> 9) & 1;
        int cs   = (k >> 10) & 1;
        int tap  = k >> 11;
        int oc = mt * 16 + (lane & 15);
        int c  = cs * 32 + (lane >> 4) * 8 + j;
        wof[k] = (oc < OFFCH) ? (_Float16)wo[(oc * CIN + c) * 9 + tap] : (_Float16)0.f;
    }
}

// ---------------- fused: stage(NCHW f32 -> f16 band) + offset conv + deformable conv ----------------
// Grid 256 = (b, yquad); 1024 threads = 16 waves; wave w: row y+(w>>2), px (w&3)*32+{0,16}+l15.
// N=32/wave. Rows [y-2, y+5] staged in LDS (128 KB) directly from x (transpose in registers).
// Bilinear records in producer-lane registers, consumed via __shfl.
// Fallback guarded by ONE wave-uniform flag computed after record build (single code copy).
__global__ __launch_bounds__(1024, 4) void fused_deform_kernel(
    const float* __restrict__ x, const f16x8* __restrict__ wof,
    const f16x8* __restrict__ wdf, const float* __restrict__ bias,
    float* __restrict__ out)
{
    __shared__ _Float16 band[8 * 128 * CIN];       // 128 KB; chunk-swizzled per pixel

    int bid  = blockIdx.x;           // 256
    int b    = bid & 7;              // one batch per XCD
    int y    = (bid >> 3) * 4;       // block covers rows y..y+3
    int tid  = threadIdx.x;
    int lane = tid & 63;
    int wave = tid >> 6;             // 0..15
    int l15  = lane & 15;
    int lk   = lane >> 4;
    int yo   = y + (wave >> 2);      // this wave's output row
    int pxbase = (wave & 3) * 32;
    int p0   = pxbase + l15;         // nt=0 pixel
    int p1   = p0 + 16;              // nt=1 pixel

    int ylo = y - 2 < 0 ? 0 : y - 2;
    int yhi = y + 5 > H - 1 ? H - 1 : y + 5;
    int nrm1 = yhi - ylo;

    const float* xbf = x + (size_t)b * CIN * HW;

    // ---- stage band rows [ylo..yhi] directly from NCHW f32 ----
    {
        int px_s = tid & 127;
        int cg   = tid >> 7;                 // channel group 0..7
        int jp_s = cg ^ (px_s & 7);
        const float* xcg = xbf + (size_t)(cg * 8) * HW + px_s;
        #pragma unroll
        for (int r = 0; r < 8; ++r) {
            int gy = ylo + r;
            if (gy > yhi) break;
            const float* xp = xcg + (size_t)gy * W;
            f16x8 v;
            #pragma unroll
            for (int j = 0; j < 8; ++j) v[j] = (_Float16)xp[(size_t)j * HW];
            *(f16x8*)&band[(((size_t)r * 128 + px_s) * 8 + jp_s) * 8] = v;
        }
    }
    __syncthreads();

    // ======== phase 1: offset conv (M=32 padded, N=32/wave, K=576), B from band ========
    f32x4 oacc[2][2];   // [mt][nt]
    #pragma unroll
    for (int mt = 0; mt < 2; ++mt)
        #pragma unroll
        for (int nt = 0; nt < 2; ++nt) oacc[mt][nt] = (f32x4){0.f, 0.f, 0.f, 0.f};

    #pragma unroll
    for (int tap = 0; tap < 9; ++tap) {
        int ky = tap / 3, kx = tap - 3 * ky;
        int yy = yo - 1 + ky;
        bool iny = (yy >= 0 && yy < H);
        int ry = yy - ylo;
        int pos0 = p0 - 1 + kx;
        int pos1 = p1 - 1 + kx;
        #pragma unroll
        for (int cs = 0; cs < 2; ++cs) {
            const f16x8* wf = wof + (size_t)((tap * 2 + cs) * 2) * 64 + lane;
            f16x8 a0 = wf[0];
            f16x8 a1 = wf[64];
            f16x8 b0 = splat8((_Float16)0.f), b1 = splat8((_Float16)0.f);
            if (iny && pos0 >= 0 && pos0 < W) {
                int jp = (cs * 4 + lk) ^ (pos0 & 7);
                b0 = *(const f16x8*)&band[(((size_t)ry * 128 + pos0) * 8 + jp) * 8];
            }
            if (iny && pos1 >= 0 && pos1 < W) {
                int jp = (cs * 4 + lk) ^ (pos1 & 7);
                b1 = *(const f16x8*)&band[(((size_t)ry * 128 + pos1) * 8 + jp) * 8];
            }
            oacc[0][0] = __builtin_amdgcn_mfma_f32_16x16x32_f16(a0, b0, oacc[0][0], 0, 0, 0);
            oacc[1][0] = __builtin_amdgcn_mfma_f32_16x16x32_f16(a1, b0, oacc[1][0], 0, 0, 0);
            oacc[0][1] = __builtin_amdgcn_mfma_f32_16x16x32_f16(a0, b1, oacc[0][1], 0, 0, 0);
            oacc[1][1] = __builtin_amdgcn_mfma_f32_16x16x32_f16(a1, b1, oacc[1][1], 0, 0, 0);
        }
    }

    // ======== record build into REGISTERS: lane (l15,lk) owns taps {2lk,2lk+1} (+8 if lk==0) ========
    uint4 rcA, rcB, rcC, rcD;                    // [tap even/odd][p0/p1]
    uint4 rc8a = {0,0,0,0}, rc8b = {0,0,0,0};    // tap 8 (valid in lk==0 lanes)
    unsigned ofA, ofB, ofC, ofD, of8a = 0, of8b = 0;

    auto build = [&](int tap, float offy, float offx, int p, uint4& rc, unsigned& of) {
        int ky = tap / 3, kx = tap - 3 * ky;
        float py  = (float)(yo - 1 + ky) + offy;
        float pxf = (float)(p  - 1 + kx) + offx;
        float y0f = floorf(py), x0f = floorf(pxf);
        float fy = py - y0f, fx = pxf - x0f;
        int y0 = (int)y0f, x0 = (int)x0f;
        int y1 = y0 + 1, x1 = x0 + 1;
        float m00 = (1.f - fy) * (1.f - fx);
        float m01 = (1.f - fy) * fx;
        float m10 = fy * (1.f - fx);
        float m11 = fy * fx;
        if (y0 < 0 || y0 >= H) { m00 = 0.f; m01 = 0.f; }
        if (y1 < 0 || y1 >= H) { m10 = 0.f; m11 = 0.f; }
        if (x0 < 0 || x0 >= W) { m00 = 0.f; m10 = 0.f; }
        if (x1 < 0 || x1 >= W) { m01 = 0.f; m11 = 0.f; }
        int y0c = iclamp(y0, 0, H - 1), y1c = iclamp(y1, 0, H - 1);
        int x0c = iclamp(x0, 0, W - 1), x1c = iclamp(x1, 0, W - 1);
        int ry0 = y0c - ylo, ry1 = y1c - ylo;
        unsigned o0 = (ry0 < 0 || ry0 > nrm1) ? 0x8000u : 0u;
        unsigned o1 = (ry1 < 0 || ry1 > nrm1) ? 0x8000u : 0u;
        int r0 = iclamp(ry0, 0, 7), r1 = iclamp(ry1, 0, 7);
        unsigned f0 = (unsigned)(((r0 * 128 + x0c) << 3) | (x0c & 7)) | o0;
        unsigned f1 = (unsigned)(((r0 * 128 + x1c) << 3) | (x1c & 7)) | o0;
        unsigned f2 = (unsigned)(((r1 * 128 + x0c) << 3) | (x0c & 7)) | o1;
        unsigned f3 = (unsigned)(((r1 * 128 + x1c) << 3) | (x1c & 7)) | o1;
        rc.x = packh2(m00, m01);
        rc.y = packh2(m10, m11);
        rc.z = f0 | (f1 << 16);
        rc.w = f2 | (f3 << 16);
        of   = packh2(offy, offx);
    };
    build(2 * lk,     oacc[0][0][0], oacc[0][0][1], p0, rcA, ofA);
    build(2 * lk + 1, oacc[0][0][2], oacc[0][0][3], p0, rcB, ofB);
    build(2 * lk,     oacc[0][1][0], oacc[0][1][1], p1, rcC, ofC);
    build(2 * lk + 1, oacc[0][1][2], oacc[0][1][3], p1, rcD, ofD);
    if (lk == 0) {
        build(8, oacc[1][0][0], oacc[1][0][1], p0, rc8a, of8a);
        build(8, oacc[1][1][0], oacc[1][1][1], p1, rc8b, of8b);
    }

    // hoisted fallback detection: ONE wave-level flag for the whole phase 2
    unsigned flagbits = (rcA.z | rcA.w | rcB.z | rcB.w | rcC.z | rcC.w | rcD.z | rcD.w
                       | rc8a.z | rc8a.w | rc8b.z | rc8b.w) & 0x80008000u;
    bool anyfall = __any(flagbits != 0);

    // ======== phase 2: deformable conv (M=64, N=32/wave, K=576) ========
    f32x4 acc[4][2];   // [mt][nt]
    #pragma unroll
    for (int mt = 0; mt < 4; ++mt)
        #pragma unroll
        for (int nt = 0; nt < 2; ++nt) acc[mt][nt] = (f32x4){0.f, 0.f, 0.f, 0.f};

    const char* bb = (const char*)band;

    #pragma unroll
    for (int tap = 0; tap < 9; ++tap) {
        int src = (tap < 8) ? ((tap >> 1) * 16 + l15) : l15;
        f16x8 bfr[2][2];   // [cs][nt]
        #pragma unroll
        for (int nt = 0; nt < 2; ++nt) {
            int pp = nt ? p1 : p0;
            uint4 rsel;
            unsigned osel;
            if (tap < 8) {
                if (tap & 1) { rsel = nt ? rcD : rcB; osel = nt ? ofD : ofB; }
                else         { rsel = nt ? rcC : rcA; osel = nt ? ofC : ofA; }
            } else         { rsel = nt ? rc8b : rc8a; osel = nt ? of8b : of8a; }
            uint4 rc;
            rc.x = (unsigned)__shfl((int)rsel.x, src, 64);
            rc.y = (unsigned)__shfl((int)rsel.y, src, 64);
            rc.z = (unsigned)__shfl((int)rsel.z, src, 64);
            rc.w = (unsigned)__shfl((int)rsel.w, src, 64);

            union { unsigned u; _Float16 h[2]; } mA, mB;
            mA.u = rc.x; mB.u = rc.y;
            _Float16 h00 = mA.h[0], h01 = mA.h[1], h10 = mB.h[0], h11 = mB.h[1];
            int f0 = rc.z & 0xffff, f1 = rc.z >> 16;
            int f2 = rc.w & 0xffff, f3 = rc.w >> 16;
            int a00 = (((f0 >> 3) & 1023) << 7) + ((lk ^ (f0 & 7)) << 4);
            int a01 = (((f1 >> 3) & 1023) << 7) + ((lk ^ (f1 & 7)) << 4);
            int a10 = (((f2 >> 3) & 1023) << 7) + ((lk ^ (f2 & 7)) << 4);
            int a11 = (((f3 >> 3) & 1023) << 7) + ((lk ^ (f3 & 7)) << 4);

            f16x8 g00 = *(const f16x8*)(bb + a00);
            f16x8 g01 = *(const f16x8*)(bb + a01);
            f16x8 g10 = *(const f16x8*)(bb + a10);
            f16x8 g11 = *(const f16x8*)(bb + a11);
            bfr[0][nt] = g00 * splat8(h00) + g01 * splat8(h01)
                       + g10 * splat8(h10) + g11 * splat8(h11);
            f16x8 k00 = *(const f16x8*)(bb + (a00 ^ 64));
            f16x8 k01 = *(const f16x8*)(bb + (a01 ^ 64));
            f16x8 k10 = *(const f16x8*)(bb + (a10 ^ 64));
            f16x8 k11 = *(const f16x8*)(bb + (a11 ^ 64));
            bfr[1][nt] = k00 * splat8(h00) + k01 * splat8(h01)
                       + k10 * splat8(h10) + k11 * splat8(h11);

            if (anyfall) {   // wave-uniform; never taken for this data, skipped via execz
                bool fall = ((rc.z | rc.w) & 0x80008000u) != 0;
                unsigned ofu = (unsigned)__shfl((int)osel, src, 64);
                if (fall) {   // rare: corner row outside staged band -> NCHW f32 gather
                    union { unsigned u; _Float16 h[2]; } of;
                    of.u = ofu;
                    float offy = (float)of.h[0], offx = (float)of.h[1];
                    int ky = tap / 3, kx = tap - 3 * ky;
                    float py  = (float)(yo - 1 + ky) + offy;
                    float pxf = (float)(pp - 1 + kx) + offx;
                    float y0f = floorf(py), x0f = floorf(pxf);
                    float fy = py - y0f, fx = pxf - x0f;
                    int y0 = (int)y0f, x0 = (int)x0f;
                    int y1 = y0 + 1, x1 = x0 + 1;
                    float n00 = (1.f - fy) * (1.f - fx);
                    float n01 = (1.f - fy) * fx;
                    float n10 = fy * (1.f - fx);
                    float n11 = fy * fx;
                    if (y0 < 0 || y0 >= H) { n00 = 0.f; n01 = 0.f; }
                    if (y1 < 0 || y1 >= H) { n10 = 0.f; n11 = 0.f; }
                    if (x0 < 0 || x0 >= W) { n00 = 0.f; n10 = 0.f; }
                    if (x1 < 0 || x1 >= W) { n01 = 0.f; n11 = 0.f; }
                    int y0c = iclamp(y0, 0, H - 1), y1c = iclamp(y1, 0, H - 1);
                    int x0c = iclamp(x0, 0, W - 1), x1c = iclamp(x1, 0, W - 1);
                    int i00 = y0c * W + x0c, i01 = y0c * W + x1c;
                    int i10 = y1c * W + x0c, i11 = y1c * W + x1c;
                    #pragma unroll
                    for (int cs = 0; cs < 2; ++cs) {
                        const float* xc = xbf + (size_t)(cs * 32 + lk * 8) * HW;
                        #pragma unroll
                        for (int j = 0; j < 8; ++j) {
                            float v = n00 * xc[i00] + n01 * xc[i01]
                                    + n10 * xc[i10] + n11 * xc[i11];
                            bfr[cs][nt][j] = (_Float16)v;
                            xc += HW;
                        }
                    }
                }
            }
        }

        #pragma unroll
        for (int cs = 0; cs < 2; ++cs) {
            const f16x8* wf = wdf + (size_t)((tap * 2 + cs) * 4) * 64 + lane;
            #pragma unroll
            for (int mt = 0; mt < 4; ++mt) {
                f16x8 af = wf[mt * 64];
                acc[mt][0] = __builtin_amdgcn_mfma_f32_16x16x32_f16(af, bfr[cs][0], acc[mt][0], 0, 0, 0);
                acc[mt][1] = __builtin_amdgcn_mfma_f32_16x16x32_f16(af, bfr[cs][1], acc[mt][1], 0, 0, 0);
            }
        }
    }

    #pragma unroll
    for (int mt = 0; mt < 4; ++mt) {
        #pragma unroll
        for (int nt = 0; nt < 2; ++nt) {
            int pp = nt ? p1 : p0;
            #pragma unroll
            for (int r = 0; r < 4; ++r) {
                int oc = mt * 16 + lk * 4 + r;
                out[((size_t)b * OCH + oc) * HW + (size_t)yo * W + pp] = acc[mt][nt][r] + bias[oc];
            }
        }
    }
}

extern "C" void kernel_launch(void* const* d_in, const int* in_sizes, int n_in,
                              void* d_out, int out_size, void* d_ws, size_t ws_size,
                              hipStream_t stream) {
    const float* x     = (const float*)d_in[0];
    const float* w_off = (const float*)d_in[1];
    const float* w_def = (const float*)d_in[2];
    const float* b_def = (const float*)d_in[3];
    float* out = (float*)d_out;

    _Float16* wdf = (_Float16*)d_ws;                 // 36,864 f16
    _Float16* wof = wdf + 36864;                     // 18,432 f16

    prep_w_kernel<<<(36864 + 18432 + 255) / 256, 256, 0, stream>>>(w_def, w_off, wdf, wof);
    fused_deform_kernel<<<BATCH * H / 4, 1024, 0, stream>>>(
        x, (const f16x8*)wof, (const f16x8*)wdf, b_def, out);
}